// Round 1
// baseline (458.260 us; speedup 1.0000x reference)
//
#include <hip/hip_runtime.h>

#define DCH 128

// ---------------- histogram of destination degrees ----------------
__global__ void k_hist(const int* __restrict__ col, int* __restrict__ cnt, int E) {
    int e = blockIdx.x * blockDim.x + threadIdx.x;
    if (e < E) atomicAdd(&cnt[col[e]], 1);
}

// ---------------- 3-kernel exclusive scan over cnt -> off ----------------
__global__ void k_scan1(const int* __restrict__ cnt, int* __restrict__ off,
                        int* __restrict__ bsums, int n) {
    __shared__ int s[1024];
    int tid = threadIdx.x;
    int idx = blockIdx.x * 1024 + tid;
    int v = (idx < n) ? cnt[idx] : 0;
    s[tid] = v;
    __syncthreads();
    for (int o = 1; o < 1024; o <<= 1) {
        int t = (tid >= o) ? s[tid - o] : 0;
        __syncthreads();
        s[tid] += t;
        __syncthreads();
    }
    if (idx < n) off[idx] = s[tid] - v;      // exclusive within block
    if (tid == 1023) bsums[blockIdx.x] = s[1023];
}

__global__ void k_scan2(int* __restrict__ bsums, int nb) {
    __shared__ int s[1024];
    int tid = threadIdx.x;
    int v = (tid < nb) ? bsums[tid] : 0;
    s[tid] = v;
    __syncthreads();
    for (int o = 1; o < 1024; o <<= 1) {
        int t = (tid >= o) ? s[tid - o] : 0;
        __syncthreads();
        s[tid] += t;
        __syncthreads();
    }
    if (tid < nb) bsums[tid] = s[tid] - v;   // exclusive block offsets
}

__global__ void k_scan3(int* __restrict__ off, const int* __restrict__ bsums, int n) {
    int idx = blockIdx.x * 1024 + threadIdx.x;
    if (idx < n) off[idx] += bsums[blockIdx.x];
}

// ---------------- bucket-scatter edges into CSR order ----------------
__global__ void k_scatter(const int* __restrict__ row, const int* __restrict__ col,
                          int* __restrict__ cur, int* __restrict__ srow, int E) {
    int e = blockIdx.x * blockDim.x + threadIdx.x;
    if (e < E) {
        int c = col[e];
        int pos = atomicAdd(&cur[c], 1);
        srow[pos] = row[e];
    }
}

// ---------------- y = (x @ W) * rsqrt(deg)  (fp32 vector GEMM) ----------------
// BM=64 rows/block, 256 threads, thread tile 8 rows x 4 cols, k-chunks of 32.
__global__ __launch_bounds__(256) void k_gemm(const float* __restrict__ x,
                                              const float* __restrict__ W,
                                              const int* __restrict__ cnt,
                                              float* __restrict__ y, int n) {
    __shared__ __align__(16) float xs[64 * 36];    // [row][k], pad 36 breaks bank conflicts
    __shared__ __align__(16) float wsh[32 * 128];  // [k][c]
    int tid = threadIdx.x;
    int tx = tid & 31;         // col group: c0 = tx*4
    int ty = tid >> 5;         // row group: r0 = ty*8
    int c0 = tx * 4;
    int r0 = ty * 8;
    int rowBase = blockIdx.x * 64;

    float acc[8][4];
#pragma unroll
    for (int i = 0; i < 8; ++i)
#pragma unroll
        for (int j = 0; j < 4; ++j) acc[i][j] = 0.f;

    for (int kc = 0; kc < DCH; kc += 32) {
        // stage x[rowBase..+63][kc..kc+31]
        {
            int r = tid >> 3;            // 0..31
            int kq = (tid & 7) * 4;      // 0,4,..28
#pragma unroll
            for (int it = 0; it < 2; ++it) {
                int rr = r + 32 * it;
                int gr = rowBase + rr;
                int grc = (gr < n) ? gr : (n - 1);
                float4 v = *(const float4*)&x[(size_t)grc * DCH + kc + kq];
                *(float4*)&xs[rr * 36 + kq] = v;
            }
        }
        // stage W[kc..kc+31][0..127]
        {
#pragma unroll
            for (int it = 0; it < 4; ++it) {
                int f = tid + 256 * it;      // float4 index 0..1023
                int kk = f >> 5;             // 0..31
                int cc = (f & 31) * 4;
                float4 v = *(const float4*)&W[(size_t)(kc + kk) * DCH + cc];
                *(float4*)&wsh[kk * DCH + cc] = v;
            }
        }
        __syncthreads();
#pragma unroll 8
        for (int kk = 0; kk < 32; ++kk) {
            float4 wv = *(const float4*)&wsh[kk * DCH + c0];
#pragma unroll
            for (int i = 0; i < 8; ++i) {
                float xv = xs[(r0 + i) * 36 + kk];
                acc[i][0] = fmaf(xv, wv.x, acc[i][0]);
                acc[i][1] = fmaf(xv, wv.y, acc[i][1]);
                acc[i][2] = fmaf(xv, wv.z, acc[i][2]);
                acc[i][3] = fmaf(xv, wv.w, acc[i][3]);
            }
        }
        __syncthreads();
    }

#pragma unroll
    for (int i = 0; i < 8; ++i) {
        int gr = rowBase + r0 + i;
        if (gr < n) {
            float s = rsqrtf((float)(cnt[gr] + 1));
            float4 v;
            v.x = acc[i][0] * s; v.y = acc[i][1] * s;
            v.z = acc[i][2] * s; v.w = acc[i][3] * s;
            *(float4*)&y[(size_t)gr * DCH + c0] = v;
        }
    }
}

// ---------------- per-node gather-aggregate + bias + ReLU ----------------
__global__ void k_agg(const float* __restrict__ y, const int* __restrict__ srow,
                      const int* __restrict__ off, const int* __restrict__ cnt,
                      const float* __restrict__ b, float* __restrict__ out,
                      int n, int E) {
    int i = blockIdx.x;
    int d = threadIdx.x;
    int s = off[i];
    int e = (i + 1 < n) ? off[i + 1] : E;
    float acc = y[(size_t)i * DCH + d];           // self-loop term (y already has dinv[row])
    int j = s;
    for (; j + 1 < e; j += 2) {
        int r0 = srow[j];
        int r1 = srow[j + 1];
        float v0 = y[(size_t)r0 * DCH + d];
        float v1 = y[(size_t)r1 * DCH + d];
        acc += v0;
        acc += v1;
    }
    if (j < e) acc += y[(size_t)srow[j] * DCH + d];
    float sc = rsqrtf((float)(cnt[i] + 1));
    float v = sc * acc + b[d];
    out[(size_t)i * DCH + d] = fmaxf(v, 0.f);
}

extern "C" void kernel_launch(void* const* d_in, const int* in_sizes, int n_in,
                              void* d_out, int out_size, void* d_ws, size_t ws_size,
                              hipStream_t stream) {
    const float* x = (const float*)d_in[0];
    const int* ei  = (const int*)d_in[1];
    const float* W = (const float*)d_in[2];
    const float* b = (const float*)d_in[3];
    float* out = (float*)d_out;

    int n = in_sizes[0] / DCH;     // 100000
    int E = in_sizes[1] / 2;       // 1600000
    const int* row = ei;           // edge_index[0] = source
    const int* col = ei + E;       // edge_index[1] = destination

    char* ws = (char*)d_ws;
    size_t o = 0;
    auto alloc = [&](size_t bytes) -> void* {
        o = (o + 255) & ~(size_t)255;
        void* p = ws + o;
        o += bytes;
        return p;
    };
    int* cnt   = (int*)alloc((size_t)n * 4);
    int* off   = (int*)alloc((size_t)(n + 1) * 4);
    int* cur   = (int*)alloc((size_t)n * 4);
    int* bs    = (int*)alloc(1024 * 4);
    int* srow  = (int*)alloc((size_t)E * 4);
    float* y   = (float*)alloc((size_t)n * DCH * 4);

    hipMemsetAsync(cnt, 0, (size_t)n * 4, stream);
    k_hist<<<(E + 255) / 256, 256, 0, stream>>>(col, cnt, E);
    int nb = (n + 1023) / 1024;    // 98
    k_scan1<<<nb, 1024, 0, stream>>>(cnt, off, bs, n);
    k_scan2<<<1, 1024, 0, stream>>>(bs, nb);
    k_scan3<<<nb, 1024, 0, stream>>>(off, bs, n);
    hipMemcpyAsync(cur, off, (size_t)n * 4, hipMemcpyDeviceToDevice, stream);
    k_scatter<<<(E + 255) / 256, 256, 0, stream>>>(row, col, cur, srow, E);
    k_gemm<<<(n + 63) / 64, 256, 0, stream>>>(x, W, cnt, y, n);
    k_agg<<<n, DCH, 0, stream>>>(y, srow, off, cnt, b, out, n, E);
}

// Round 2
// 375.346 us; speedup vs baseline: 1.2209x; 1.2209x over previous
//
#include <hip/hip_runtime.h>

#define DCH 128
#define T_PART 4096
#define B_MAX 512
#define NODES_PER_BUCKET 256

// ---------------- histogram of destination degrees ----------------
__global__ void k_hist(const int* __restrict__ col, int* __restrict__ cnt, int E) {
    int e = blockIdx.x * blockDim.x + threadIdx.x;
    if (e < E) atomicAdd(&cnt[col[e]], 1);
}

// ---------------- 3-kernel exclusive scan over cnt -> off ----------------
__global__ void k_scan1(const int* __restrict__ cnt, int* __restrict__ off,
                        int* __restrict__ bsums, int n) {
    __shared__ int s[1024];
    int tid = threadIdx.x;
    int idx = blockIdx.x * 1024 + tid;
    int v = (idx < n) ? cnt[idx] : 0;
    s[tid] = v;
    __syncthreads();
    for (int o = 1; o < 1024; o <<= 1) {
        int t = (tid >= o) ? s[tid - o] : 0;
        __syncthreads();
        s[tid] += t;
        __syncthreads();
    }
    if (idx < n) off[idx] = s[tid] - v;      // exclusive within block
    if (tid == 1023) bsums[blockIdx.x] = s[1023];
}

__global__ void k_scan2(int* __restrict__ bsums, int nb) {
    __shared__ int s[1024];
    int tid = threadIdx.x;
    int v = (tid < nb) ? bsums[tid] : 0;
    s[tid] = v;
    __syncthreads();
    for (int o = 1; o < 1024; o <<= 1) {
        int t = (tid >= o) ? s[tid - o] : 0;
        __syncthreads();
        s[tid] += t;
        __syncthreads();
    }
    if (tid < nb) bsums[tid] = s[tid] - v;   // exclusive block offsets
}

__global__ void k_scan3(int* __restrict__ off, const int* __restrict__ bsums, int n) {
    int idx = blockIdx.x * 1024 + threadIdx.x;
    if (idx < n) off[idx] += bsums[blockIdx.x];
}

// ---------------- pass 1: LDS-binned coarse partition ----------------
// Each block stages T_PART edges, bins them by dest>>8 into <=512 buckets in
// LDS, reserves global space with ONE atomicAdd per bucket, and flushes each
// bucket's run as a contiguous burst. Kills the 16x write amplification of
// the naive random scatter (4B random writes -> 64B line writebacks).
__global__ __launch_bounds__(512) void k_part(const int* __restrict__ row,
                                              const int* __restrict__ col,
                                              unsigned int* __restrict__ coarse,
                                              int* __restrict__ gcount,
                                              int E, int B, int CAP) {
    __shared__ int hist[B_MAX];     // per-bucket count in this tile
    __shared__ int basex[B_MAX];    // exclusive scan of hist
    __shared__ int curx[B_MAX];     // running cursor for LDS compaction
    __shared__ int gb[B_MAX];       // reserved global base per bucket
    __shared__ unsigned int spack[T_PART];
    __shared__ unsigned short sbuck[T_PART];

    int tid = threadIdx.x;
    int base_e = blockIdx.x * T_PART;
    int tileCnt = min(T_PART, E - base_e);

    hist[tid] = 0;
    __syncthreads();

    int er[8], ec[8];
#pragma unroll
    for (int i = 0; i < 8; ++i) {
        int e = base_e + tid + i * 512;
        if (e < E) {
            er[i] = row[e];
            ec[i] = col[e];
            atomicAdd(&hist[ec[i] >> 8], 1);
        } else {
            er[i] = -1;
            ec[i] = 0;
        }
    }
    __syncthreads();

    // Hillis-Steele inclusive scan over 512 entries (basex as scan buffer)
    int v = hist[tid];
    basex[tid] = v;
    __syncthreads();
    for (int o = 1; o < 512; o <<= 1) {
        int t = (tid >= o) ? basex[tid - o] : 0;
        __syncthreads();
        basex[tid] += t;
        __syncthreads();
    }
    int excl = basex[tid] - v;
    __syncthreads();
    basex[tid] = excl;
    curx[tid] = excl;
    if (tid < B) gb[tid] = (v > 0) ? atomicAdd(&gcount[tid], v) : gcount[tid];
    else gb[tid] = 0;
    __syncthreads();

    // compact into LDS, bucket-sorted
#pragma unroll
    for (int i = 0; i < 8; ++i) {
        if (er[i] >= 0) {
            int b = ec[i] >> 8;
            int slot = atomicAdd(&curx[b], 1);
            spack[slot] = ((unsigned int)er[i] << 8) | (unsigned int)(ec[i] & 255);
            sbuck[slot] = (unsigned short)b;
        }
    }
    __syncthreads();

    // flush: consecutive slots of one bucket -> consecutive global addresses
    for (int s = tid; s < tileCnt; s += 512) {
        int b = sbuck[s];
        int dst = gb[b] + (s - basex[b]);
        if (dst < CAP) coarse[(size_t)b * CAP + dst] = spack[s];
    }
}

// ---------------- pass 2: coarse bucket -> exact CSR ----------------
// Writes confined to a ~16 KB contiguous srow window per block (L2-resident).
__global__ __launch_bounds__(256) void k_csr(const unsigned int* __restrict__ coarse,
                                             const int* __restrict__ gcount,
                                             const int* __restrict__ off,
                                             int* __restrict__ srow,
                                             int n, int CAP) {
    __shared__ int cur[NODES_PER_BUCKET];
    int b = blockIdx.x;
    int nodeBase = b << 8;
    int tid = threadIdx.x;
    if (nodeBase + tid < n) cur[tid] = off[nodeBase + tid];
    __syncthreads();
    int cnt = min(gcount[b], CAP);
    for (int s = tid; s < cnt; s += 256) {
        unsigned int p = coarse[(size_t)b * CAP + s];
        int d = (int)(p & 255u);
        int pos = atomicAdd(&cur[d], 1);
        srow[pos] = (int)(p >> 8);
    }
}

// ---------------- y = (x @ W) * rsqrt(deg)  (fp32 vector GEMM) ----------------
__global__ __launch_bounds__(256) void k_gemm(const float* __restrict__ x,
                                              const float* __restrict__ W,
                                              const int* __restrict__ cnt,
                                              float* __restrict__ y, int n) {
    __shared__ __align__(16) float xs[64 * 36];    // [row][k], pad 36
    __shared__ __align__(16) float wsh[32 * 128];  // [k][c]
    int tid = threadIdx.x;
    int tx = tid & 31;
    int ty = tid >> 5;
    int c0 = tx * 4;
    int r0 = ty * 8;
    int rowBase = blockIdx.x * 64;

    float acc[8][4];
#pragma unroll
    for (int i = 0; i < 8; ++i)
#pragma unroll
        for (int j = 0; j < 4; ++j) acc[i][j] = 0.f;

    for (int kc = 0; kc < DCH; kc += 32) {
        {
            int r = tid >> 3;
            int kq = (tid & 7) * 4;
#pragma unroll
            for (int it = 0; it < 2; ++it) {
                int rr = r + 32 * it;
                int gr = rowBase + rr;
                int grc = (gr < n) ? gr : (n - 1);
                float4 v = *(const float4*)&x[(size_t)grc * DCH + kc + kq];
                *(float4*)&xs[rr * 36 + kq] = v;
            }
        }
        {
#pragma unroll
            for (int it = 0; it < 4; ++it) {
                int f = tid + 256 * it;
                int kk = f >> 5;
                int cc = (f & 31) * 4;
                float4 v = *(const float4*)&W[(size_t)(kc + kk) * DCH + cc];
                *(float4*)&wsh[kk * DCH + cc] = v;
            }
        }
        __syncthreads();
#pragma unroll 8
        for (int kk = 0; kk < 32; ++kk) {
            float4 wv = *(const float4*)&wsh[kk * DCH + c0];
#pragma unroll
            for (int i = 0; i < 8; ++i) {
                float xv = xs[(r0 + i) * 36 + kk];
                acc[i][0] = fmaf(xv, wv.x, acc[i][0]);
                acc[i][1] = fmaf(xv, wv.y, acc[i][1]);
                acc[i][2] = fmaf(xv, wv.z, acc[i][2]);
                acc[i][3] = fmaf(xv, wv.w, acc[i][3]);
            }
        }
        __syncthreads();
    }

#pragma unroll
    for (int i = 0; i < 8; ++i) {
        int gr = rowBase + r0 + i;
        if (gr < n) {
            float s = rsqrtf((float)(cnt[gr] + 1));
            float4 v;
            v.x = acc[i][0] * s; v.y = acc[i][1] * s;
            v.z = acc[i][2] * s; v.w = acc[i][3] * s;
            *(float4*)&y[(size_t)gr * DCH + c0] = v;
        }
    }
}

// ---------------- per-node gather-aggregate + bias + ReLU ----------------
__global__ void k_agg(const float* __restrict__ y, const int* __restrict__ srow,
                      const int* __restrict__ off, const int* __restrict__ cnt,
                      const float* __restrict__ b, float* __restrict__ out,
                      int n, int E) {
    int i = blockIdx.x;
    int d = threadIdx.x;
    int s = off[i];
    int e = (i + 1 < n) ? off[i + 1] : E;
    float acc = y[(size_t)i * DCH + d];           // self-loop term
    int j = s;
    for (; j + 1 < e; j += 2) {
        int r0 = srow[j];
        int r1 = srow[j + 1];
        float v0 = y[(size_t)r0 * DCH + d];
        float v1 = y[(size_t)r1 * DCH + d];
        acc += v0;
        acc += v1;
    }
    if (j < e) acc += y[(size_t)srow[j] * DCH + d];
    float sc = rsqrtf((float)(cnt[i] + 1));
    float v = sc * acc + b[d];
    out[(size_t)i * DCH + d] = fmaxf(v, 0.f);
}

extern "C" void kernel_launch(void* const* d_in, const int* in_sizes, int n_in,
                              void* d_out, int out_size, void* d_ws, size_t ws_size,
                              hipStream_t stream) {
    const float* x = (const float*)d_in[0];
    const int* ei  = (const int*)d_in[1];
    const float* W = (const float*)d_in[2];
    const float* b = (const float*)d_in[3];
    float* out = (float*)d_out;

    int n = in_sizes[0] / DCH;     // 100000
    int E = in_sizes[1] / 2;       // 1600000
    const int* row = ei;           // sources
    const int* col = ei + E;       // destinations

    int B = (n + NODES_PER_BUCKET - 1) / NODES_PER_BUCKET;   // 391
    int CAP = 6144;                // avg 4096 edges/bucket, +32 sigma headroom

    char* ws = (char*)d_ws;
    size_t o = 0;
    auto alloc = [&](size_t bytes) -> void* {
        o = (o + 255) & ~(size_t)255;
        void* p = ws + o;
        o += bytes;
        return p;
    };
    int* cnt     = (int*)alloc((size_t)n * 4);
    int* off     = (int*)alloc((size_t)(n + 1) * 4);
    int* bs      = (int*)alloc(1024 * 4);
    int* gcount  = (int*)alloc((size_t)B * 4);
    int* srow    = (int*)alloc((size_t)E * 4);
    float* y     = (float*)alloc((size_t)n * DCH * 4);
    // coarse buffer aliases y: dead before k_gemm writes y
    unsigned int* coarse = (unsigned int*)y;     // B*CAP*4 = 9.6 MB <= 51.2 MB

    hipMemsetAsync(cnt, 0, (size_t)n * 4, stream);
    hipMemsetAsync(gcount, 0, (size_t)B * 4, stream);
    k_hist<<<(E + 255) / 256, 256, 0, stream>>>(col, cnt, E);
    int nb = (n + 1023) / 1024;    // 98
    k_scan1<<<nb, 1024, 0, stream>>>(cnt, off, bs, n);
    k_scan2<<<1, 1024, 0, stream>>>(bs, nb);
    k_scan3<<<nb, 1024, 0, stream>>>(off, bs, n);
    int nt = (E + T_PART - 1) / T_PART;  // 391
    k_part<<<nt, 512, 0, stream>>>(row, col, coarse, gcount, E, B, CAP);
    k_csr<<<B, 256, 0, stream>>>(coarse, gcount, off, srow, n, CAP);
    k_gemm<<<(n + 63) / 64, 256, 0, stream>>>(x, W, cnt, y, n);
    k_agg<<<n, DCH, 0, stream>>>(y, srow, off, cnt, b, out, n, E);
}

// Round 3
// 296.590 us; speedup vs baseline: 1.5451x; 1.2655x over previous
//
#include <hip/hip_runtime.h>

#define DCH 128
#define T_PART 4096
#define B_MAX 512
#define NODES_PER_BUCKET 256

typedef short bf16x8 __attribute__((ext_vector_type(8)));
typedef float f32x4 __attribute__((ext_vector_type(4)));

__device__ inline unsigned short f2bf(float f) {
    unsigned int u = __float_as_uint(f);
    unsigned int r = (u + 0x7fffu + ((u >> 16) & 1u)) >> 16;
    return (unsigned short)r;
}

__device__ inline float2 bf2_to_f2(unsigned int p) {
    float2 r;
    r.x = __uint_as_float(p << 16);
    r.y = __uint_as_float(p & 0xffff0000u);
    return r;
}

// ---------------- histogram of destination degrees ----------------
__global__ void k_hist(const int* __restrict__ col, int* __restrict__ cnt, int E) {
    int e = blockIdx.x * blockDim.x + threadIdx.x;
    if (e < E) atomicAdd(&cnt[col[e]], 1);
}

// ---------------- 3-kernel exclusive scan over cnt -> off ----------------
__global__ void k_scan1(const int* __restrict__ cnt, int* __restrict__ off,
                        int* __restrict__ bsums, int n) {
    __shared__ int s[1024];
    int tid = threadIdx.x;
    int idx = blockIdx.x * 1024 + tid;
    int v = (idx < n) ? cnt[idx] : 0;
    s[tid] = v;
    __syncthreads();
    for (int o = 1; o < 1024; o <<= 1) {
        int t = (tid >= o) ? s[tid - o] : 0;
        __syncthreads();
        s[tid] += t;
        __syncthreads();
    }
    if (idx < n) off[idx] = s[tid] - v;
    if (tid == 1023) bsums[blockIdx.x] = s[1023];
}

__global__ void k_scan2(int* __restrict__ bsums, int nb) {
    __shared__ int s[1024];
    int tid = threadIdx.x;
    int v = (tid < nb) ? bsums[tid] : 0;
    s[tid] = v;
    __syncthreads();
    for (int o = 1; o < 1024; o <<= 1) {
        int t = (tid >= o) ? s[tid - o] : 0;
        __syncthreads();
        s[tid] += t;
        __syncthreads();
    }
    if (tid < nb) bsums[tid] = s[tid] - v;
}

__global__ void k_scan3(int* __restrict__ off, const int* __restrict__ bsums, int n) {
    int idx = blockIdx.x * 1024 + threadIdx.x;
    if (idx < n) off[idx] += bsums[blockIdx.x];
}

// ---------------- pass 1: LDS-binned coarse partition ----------------
__global__ __launch_bounds__(512) void k_part(const int* __restrict__ row,
                                              const int* __restrict__ col,
                                              unsigned int* __restrict__ coarse,
                                              int* __restrict__ gcount,
                                              int E, int B, int CAP) {
    __shared__ int hist[B_MAX];
    __shared__ int basex[B_MAX];
    __shared__ int curx[B_MAX];
    __shared__ int gb[B_MAX];
    __shared__ unsigned int spack[T_PART];
    __shared__ unsigned short sbuck[T_PART];

    int tid = threadIdx.x;
    int base_e = blockIdx.x * T_PART;
    int tileCnt = min(T_PART, E - base_e);

    hist[tid] = 0;
    __syncthreads();

    int er[8], ec[8];
#pragma unroll
    for (int i = 0; i < 8; ++i) {
        int e = base_e + tid + i * 512;
        if (e < E) {
            er[i] = row[e];
            ec[i] = col[e];
            atomicAdd(&hist[ec[i] >> 8], 1);
        } else {
            er[i] = -1;
            ec[i] = 0;
        }
    }
    __syncthreads();

    int v = hist[tid];
    basex[tid] = v;
    __syncthreads();
    for (int o = 1; o < 512; o <<= 1) {
        int t = (tid >= o) ? basex[tid - o] : 0;
        __syncthreads();
        basex[tid] += t;
        __syncthreads();
    }
    int excl = basex[tid] - v;
    __syncthreads();
    basex[tid] = excl;
    curx[tid] = excl;
    if (tid < B) gb[tid] = (v > 0) ? atomicAdd(&gcount[tid], v) : gcount[tid];
    else gb[tid] = 0;
    __syncthreads();

#pragma unroll
    for (int i = 0; i < 8; ++i) {
        if (er[i] >= 0) {
            int b = ec[i] >> 8;
            int slot = atomicAdd(&curx[b], 1);
            spack[slot] = ((unsigned int)er[i] << 8) | (unsigned int)(ec[i] & 255);
            sbuck[slot] = (unsigned short)b;
        }
    }
    __syncthreads();

    for (int s = tid; s < tileCnt; s += 512) {
        int b = sbuck[s];
        int dst = gb[b] + (s - basex[b]);
        if (dst < CAP) coarse[(size_t)b * CAP + dst] = spack[s];
    }
}

// ---------------- pass 2: coarse bucket -> exact CSR ----------------
__global__ __launch_bounds__(256) void k_csr(const unsigned int* __restrict__ coarse,
                                             const int* __restrict__ gcount,
                                             const int* __restrict__ off,
                                             int* __restrict__ srow,
                                             int n, int CAP) {
    __shared__ int cur[NODES_PER_BUCKET];
    int b = blockIdx.x;
    int nodeBase = b << 8;
    int tid = threadIdx.x;
    if (nodeBase + tid < n) cur[tid] = off[nodeBase + tid];
    __syncthreads();
    int cnt = min(gcount[b], CAP);
    for (int s = tid; s < cnt; s += 256) {
        unsigned int p = coarse[(size_t)b * CAP + s];
        int d = (int)(p & 255u);
        int pos = atomicAdd(&cur[d], 1);
        srow[pos] = (int)(p >> 8);
    }
}

// ---------------- pack W into MFMA B-fragment-linear bf16 order ----------------
// Frag (nt,ks): lane holds B[k=ks*32+(lane>>4)*8+j][n=nt*16+(lane&15)], j=0..7.
__global__ void k_wfrag(const float* __restrict__ W, unsigned short* __restrict__ Wf) {
    int frag = blockIdx.x;      // 0..31 = nt*4+ks
    int lane = threadIdx.x;     // 0..63
    int nt = frag >> 2, ks = frag & 3;
    int nn = nt * 16 + (lane & 15);
    int k0 = ks * 32 + ((lane >> 4) * 8);
    unsigned short tmp[8];
#pragma unroll
    for (int j = 0; j < 8; ++j) tmp[j] = f2bf(W[(size_t)(k0 + j) * DCH + nn]);
    *(uint4*)&Wf[((size_t)frag * 64 + lane) * 8] = *(const uint4*)tmp;
}

// ---------------- y = bf16((x @ W) * rsqrt(deg))  via MFMA ----------------
// 4 waves/block, 16 rows/wave, N=128 as 8 tiles of 16. B frags from Wf (L2-hot).
__global__ __launch_bounds__(256) void k_gemm_mfma(const float* __restrict__ x,
                                                   const unsigned short* __restrict__ Wf,
                                                   const int* __restrict__ cnt,
                                                   unsigned short* __restrict__ y,
                                                   int n) {
    int tid = threadIdx.x;
    int wv = tid >> 6;
    int lane = tid & 63;
    int rowBase = blockIdx.x * 64 + wv * 16;
    int m = rowBase + (lane & 15);
    int mc = (m < n) ? m : (n - 1);
    int kq = (lane >> 4) * 8;

    f32x4 acc[8];
    f32x4 zero = {0.f, 0.f, 0.f, 0.f};
#pragma unroll
    for (int t = 0; t < 8; ++t) acc[t] = zero;

    const bf16x8* wfv = (const bf16x8*)Wf;
#pragma unroll
    for (int ks = 0; ks < 4; ++ks) {
        int kbase = ks * 32 + kq;
        float4 lo = *(const float4*)&x[(size_t)mc * DCH + kbase];
        float4 hi = *(const float4*)&x[(size_t)mc * DCH + kbase + 4];
        bf16x8 a;
        a[0] = (short)f2bf(lo.x); a[1] = (short)f2bf(lo.y);
        a[2] = (short)f2bf(lo.z); a[3] = (short)f2bf(lo.w);
        a[4] = (short)f2bf(hi.x); a[5] = (short)f2bf(hi.y);
        a[6] = (short)f2bf(hi.z); a[7] = (short)f2bf(hi.w);
#pragma unroll
        for (int nt = 0; nt < 8; ++nt) {
            bf16x8 bfr = wfv[(nt * 4 + ks) * 64 + lane];
            acc[nt] = __builtin_amdgcn_mfma_f32_16x16x32_bf16(a, bfr, acc[nt], 0, 0, 0);
        }
    }

    int orow_base = rowBase + ((lane >> 4) * 4);
#pragma unroll
    for (int r = 0; r < 4; ++r) {
        int orow = orow_base + r;
        if (orow < n) {
            float s = rsqrtf((float)(cnt[orow] + 1));
#pragma unroll
            for (int nt = 0; nt < 8; ++nt) {
                y[(size_t)orow * DCH + nt * 16 + (lane & 15)] = f2bf(acc[nt][r] * s);
            }
        }
    }
}

// ---------------- per-node gather-aggregate + bias + ReLU (bf16 y) ----------------
// 4 nodes/block, one wave per node; lane covers 2 channels via packed bf16x2.
__global__ __launch_bounds__(256) void k_agg(const unsigned int* __restrict__ y2,
                                             const int* __restrict__ srow,
                                             const int* __restrict__ off,
                                             const float* __restrict__ b,
                                             float* __restrict__ out, int n, int E) {
    int i = blockIdx.x * 4 + (threadIdx.x >> 6);
    if (i >= n) return;
    int lane = threadIdx.x & 63;
    int s = off[i];
    int e = (i + 1 < n) ? off[i + 1] : E;

    float2 acc = bf2_to_f2(y2[(size_t)i * 64 + lane]);   // self-loop
    int j = s;
    for (; j + 4 <= e; j += 4) {
        int r0 = srow[j], r1 = srow[j + 1], r2 = srow[j + 2], r3 = srow[j + 3];
        unsigned int p0 = y2[(size_t)r0 * 64 + lane];
        unsigned int p1 = y2[(size_t)r1 * 64 + lane];
        unsigned int p2 = y2[(size_t)r2 * 64 + lane];
        unsigned int p3 = y2[(size_t)r3 * 64 + lane];
        float2 f0 = bf2_to_f2(p0), f1 = bf2_to_f2(p1);
        float2 f2v = bf2_to_f2(p2), f3 = bf2_to_f2(p3);
        acc.x += (f0.x + f1.x) + (f2v.x + f3.x);
        acc.y += (f0.y + f1.y) + (f2v.y + f3.y);
    }
    for (; j < e; ++j) {
        float2 f = bf2_to_f2(y2[(size_t)srow[j] * 64 + lane]);
        acc.x += f.x;
        acc.y += f.y;
    }
    float sc = rsqrtf((float)(e - s + 1));   // deg = off[i+1]-off[i], +1 self-loop
    float2 bb = ((const float2*)b)[lane];
    float2 v;
    v.x = fmaxf(fmaf(sc, acc.x, bb.x), 0.f);
    v.y = fmaxf(fmaf(sc, acc.y, bb.y), 0.f);
    ((float2*)out)[(size_t)i * 64 + lane] = v;
}

extern "C" void kernel_launch(void* const* d_in, const int* in_sizes, int n_in,
                              void* d_out, int out_size, void* d_ws, size_t ws_size,
                              hipStream_t stream) {
    const float* x = (const float*)d_in[0];
    const int* ei  = (const int*)d_in[1];
    const float* W = (const float*)d_in[2];
    const float* b = (const float*)d_in[3];
    float* out = (float*)d_out;

    int n = in_sizes[0] / DCH;     // 100000
    int E = in_sizes[1] / 2;       // 1600000
    const int* row = ei;           // sources
    const int* col = ei + E;       // destinations

    int B = (n + NODES_PER_BUCKET - 1) / NODES_PER_BUCKET;   // 391
    int CAP = 6144;

    char* ws = (char*)d_ws;
    size_t o = 0;
    auto alloc = [&](size_t bytes) -> void* {
        o = (o + 255) & ~(size_t)255;
        void* p = ws + o;
        o += bytes;
        return p;
    };
    int* cnt     = (int*)alloc((size_t)n * 4);
    int* off     = (int*)alloc((size_t)(n + 1) * 4);
    int* bs      = (int*)alloc(1024 * 4);
    int* gcount  = (int*)alloc((size_t)B * 4);
    int* srow    = (int*)alloc((size_t)E * 4);
    unsigned short* Wf = (unsigned short*)alloc((size_t)DCH * DCH * 2);
    unsigned short* y  = (unsigned short*)alloc((size_t)n * DCH * 2);
    // coarse buffer aliases y: dead before k_gemm_mfma writes y (9.6 MB <= 25.6 MB)
    unsigned int* coarse = (unsigned int*)y;

    hipMemsetAsync(cnt, 0, (size_t)n * 4, stream);
    hipMemsetAsync(gcount, 0, (size_t)B * 4, stream);
    k_wfrag<<<32, 64, 0, stream>>>(W, Wf);
    k_hist<<<(E + 255) / 256, 256, 0, stream>>>(col, cnt, E);
    int nb = (n + 1023) / 1024;    // 98
    k_scan1<<<nb, 1024, 0, stream>>>(cnt, off, bs, n);
    k_scan2<<<1, 1024, 0, stream>>>(bs, nb);
    k_scan3<<<nb, 1024, 0, stream>>>(off, bs, n);
    int nt = (E + T_PART - 1) / T_PART;  // 391
    k_part<<<nt, 512, 0, stream>>>(row, col, coarse, gcount, E, B, CAP);
    k_csr<<<B, 256, 0, stream>>>(coarse, gcount, off, srow, n, CAP);
    k_gemm_mfma<<<(n + 63) / 64, 256, 0, stream>>>(x, Wf, cnt, y, n);
    k_agg<<<(n + 3) / 4, 256, 0, stream>>>((const unsigned int*)y, srow, off, b, out, n, E);
}

// Round 4
// 289.035 us; speedup vs baseline: 1.5855x; 1.0261x over previous
//
#include <hip/hip_runtime.h>

#define DCH 128
#define T_PART 4096
#define B_MAX 512
#define NODES_PER_BUCKET 256

typedef short bf16x8 __attribute__((ext_vector_type(8)));
typedef float f32x4 __attribute__((ext_vector_type(4)));

__device__ inline unsigned short f2bf(float f) {
    unsigned int u = __float_as_uint(f);
    unsigned int r = (u + 0x7fffu + ((u >> 16) & 1u)) >> 16;
    return (unsigned short)r;
}

// ---------------- histogram of destination degrees ----------------
__global__ void k_hist(const int* __restrict__ col, int* __restrict__ cnt, int E) {
    int e = blockIdx.x * blockDim.x + threadIdx.x;
    if (e < E) atomicAdd(&cnt[col[e]], 1);
}

// ---------------- 3-kernel exclusive scan over cnt -> off ----------------
__global__ void k_scan1(const int* __restrict__ cnt, int* __restrict__ off,
                        int* __restrict__ bsums, int n) {
    __shared__ int s[1024];
    int tid = threadIdx.x;
    int idx = blockIdx.x * 1024 + tid;
    int v = (idx < n) ? cnt[idx] : 0;
    s[tid] = v;
    __syncthreads();
    for (int o = 1; o < 1024; o <<= 1) {
        int t = (tid >= o) ? s[tid - o] : 0;
        __syncthreads();
        s[tid] += t;
        __syncthreads();
    }
    if (idx < n) off[idx] = s[tid] - v;
    if (tid == 1023) bsums[blockIdx.x] = s[1023];
}

__global__ void k_scan2(int* __restrict__ bsums, int nb) {
    __shared__ int s[1024];
    int tid = threadIdx.x;
    int v = (tid < nb) ? bsums[tid] : 0;
    s[tid] = v;
    __syncthreads();
    for (int o = 1; o < 1024; o <<= 1) {
        int t = (tid >= o) ? s[tid - o] : 0;
        __syncthreads();
        s[tid] += t;
        __syncthreads();
    }
    if (tid < nb) bsums[tid] = s[tid] - v;
}

__global__ void k_scan3(int* __restrict__ off, const int* __restrict__ bsums, int n) {
    int idx = blockIdx.x * 1024 + threadIdx.x;
    if (idx < n) off[idx] += bsums[blockIdx.x];
}

// ---------------- pass 1: LDS-binned coarse partition ----------------
__global__ __launch_bounds__(512) void k_part(const int* __restrict__ row,
                                              const int* __restrict__ col,
                                              unsigned int* __restrict__ coarse,
                                              int* __restrict__ gcount,
                                              int E, int B, int CAP) {
    __shared__ int hist[B_MAX];
    __shared__ int basex[B_MAX];
    __shared__ int curx[B_MAX];
    __shared__ int gb[B_MAX];
    __shared__ unsigned int spack[T_PART];
    __shared__ unsigned short sbuck[T_PART];

    int tid = threadIdx.x;
    int base_e = blockIdx.x * T_PART;
    int tileCnt = min(T_PART, E - base_e);

    hist[tid] = 0;
    __syncthreads();

    int er[8], ec[8];
#pragma unroll
    for (int i = 0; i < 8; ++i) {
        int e = base_e + tid + i * 512;
        if (e < E) {
            er[i] = row[e];
            ec[i] = col[e];
            atomicAdd(&hist[ec[i] >> 8], 1);
        } else {
            er[i] = -1;
            ec[i] = 0;
        }
    }
    __syncthreads();

    int v = hist[tid];
    basex[tid] = v;
    __syncthreads();
    for (int o = 1; o < 512; o <<= 1) {
        int t = (tid >= o) ? basex[tid - o] : 0;
        __syncthreads();
        basex[tid] += t;
        __syncthreads();
    }
    int excl = basex[tid] - v;
    __syncthreads();
    basex[tid] = excl;
    curx[tid] = excl;
    if (tid < B) gb[tid] = (v > 0) ? atomicAdd(&gcount[tid], v) : gcount[tid];
    else gb[tid] = 0;
    __syncthreads();

#pragma unroll
    for (int i = 0; i < 8; ++i) {
        if (er[i] >= 0) {
            int b = ec[i] >> 8;
            int slot = atomicAdd(&curx[b], 1);
            spack[slot] = ((unsigned int)er[i] << 8) | (unsigned int)(ec[i] & 255);
            sbuck[slot] = (unsigned short)b;
        }
    }
    __syncthreads();

    for (int s = tid; s < tileCnt; s += 512) {
        int b = sbuck[s];
        int dst = gb[b] + (s - basex[b]);
        if (dst < CAP) coarse[(size_t)b * CAP + dst] = spack[s];
    }
}

// ---------------- pass 2: coarse bucket -> exact CSR ----------------
__global__ __launch_bounds__(256) void k_csr(const unsigned int* __restrict__ coarse,
                                             const int* __restrict__ gcount,
                                             const int* __restrict__ off,
                                             int* __restrict__ srow,
                                             int n, int CAP) {
    __shared__ int cur[NODES_PER_BUCKET];
    int b = blockIdx.x;
    int nodeBase = b << 8;
    int tid = threadIdx.x;
    if (nodeBase + tid < n) cur[tid] = off[nodeBase + tid];
    __syncthreads();
    int cnt = min(gcount[b], CAP);
    for (int s = tid; s < cnt; s += 256) {
        unsigned int p = coarse[(size_t)b * CAP + s];
        int d = (int)(p & 255u);
        int pos = atomicAdd(&cur[d], 1);
        srow[pos] = (int)(p >> 8);
    }
}

// ---------------- pack W into MFMA B-fragment-linear bf16 order ----------------
__global__ void k_wfrag(const float* __restrict__ W, unsigned short* __restrict__ Wf) {
    int frag = blockIdx.x;      // 0..31 = nt*4+ks
    int lane = threadIdx.x;     // 0..63
    int nt = frag >> 2, ks = frag & 3;
    int nn = nt * 16 + (lane & 15);
    int k0 = ks * 32 + ((lane >> 4) * 8);
    unsigned short tmp[8];
#pragma unroll
    for (int j = 0; j < 8; ++j) tmp[j] = f2bf(W[(size_t)(k0 + j) * DCH + nn]);
    *(uint4*)&Wf[((size_t)frag * 64 + lane) * 8] = *(const uint4*)tmp;
}

// ---------------- y = bf16((x @ W) * rsqrt(deg))  via MFMA ----------------
__global__ __launch_bounds__(256) void k_gemm_mfma(const float* __restrict__ x,
                                                   const unsigned short* __restrict__ Wf,
                                                   const int* __restrict__ cnt,
                                                   unsigned short* __restrict__ y,
                                                   int n) {
    int tid = threadIdx.x;
    int wv = tid >> 6;
    int lane = tid & 63;
    int rowBase = blockIdx.x * 64 + wv * 16;
    int m = rowBase + (lane & 15);
    int mc = (m < n) ? m : (n - 1);
    int kq = (lane >> 4) * 8;

    f32x4 acc[8];
    f32x4 zero = {0.f, 0.f, 0.f, 0.f};
#pragma unroll
    for (int t = 0; t < 8; ++t) acc[t] = zero;

    const bf16x8* wfv = (const bf16x8*)Wf;
#pragma unroll
    for (int ks = 0; ks < 4; ++ks) {
        int kbase = ks * 32 + kq;
        float4 lo = *(const float4*)&x[(size_t)mc * DCH + kbase];
        float4 hi = *(const float4*)&x[(size_t)mc * DCH + kbase + 4];
        bf16x8 a;
        a[0] = (short)f2bf(lo.x); a[1] = (short)f2bf(lo.y);
        a[2] = (short)f2bf(lo.z); a[3] = (short)f2bf(lo.w);
        a[4] = (short)f2bf(hi.x); a[5] = (short)f2bf(hi.y);
        a[6] = (short)f2bf(hi.z); a[7] = (short)f2bf(hi.w);
#pragma unroll
        for (int nt = 0; nt < 8; ++nt) {
            bf16x8 bfr = wfv[(nt * 4 + ks) * 64 + lane];
            acc[nt] = __builtin_amdgcn_mfma_f32_16x16x32_bf16(a, bfr, acc[nt], 0, 0, 0);
        }
    }

    int orow_base = rowBase + ((lane >> 4) * 4);
#pragma unroll
    for (int r = 0; r < 4; ++r) {
        int orow = orow_base + r;
        if (orow < n) {
            float s = rsqrtf((float)(cnt[orow] + 1));
#pragma unroll
            for (int nt = 0; nt < 8; ++nt) {
                y[(size_t)orow * DCH + nt * 16 + (lane & 15)] = f2bf(acc[nt][r] * s);
            }
        }
    }
}

// ---------------- per-node gather-aggregate + bias + ReLU (bf16 y, uint4 gather) ----
// One wave per node. Quarter-wave q handles edge j+q: its 16 lanes load uint4
// (16 B = 8 channels) so ONE wave-load instruction gathers 4 source rows (1 KB).
// Quarters keep private 8-float partials; shfl_xor(16/32) folds them at the end.
__global__ __launch_bounds__(256) void k_agg(const uint4* __restrict__ y4,
                                             const int* __restrict__ srow,
                                             const int* __restrict__ off,
                                             const float* __restrict__ b,
                                             float* __restrict__ out, int n, int E) {
    int i = blockIdx.x * 4 + (threadIdx.x >> 6);
    if (i >= n) return;
    int lane = threadIdx.x & 63;
    int q = lane >> 4;          // quarter 0..3
    int l16 = lane & 15;        // position within quarter
    int s = off[i];
    int e = (i + 1 < n) ? off[i + 1] : E;

    float acc[8];
#pragma unroll
    for (int k = 0; k < 8; ++k) acc[k] = 0.f;

    // self-loop handled by quarter 0
    if (q == 0) {
        uint4 v = y4[(size_t)i * 16 + l16];
        unsigned int p[4] = {v.x, v.y, v.z, v.w};
#pragma unroll
        for (int t = 0; t < 4; ++t) {
            acc[2 * t]     += __uint_as_float(p[t] << 16);
            acc[2 * t + 1] += __uint_as_float(p[t] & 0xffff0000u);
        }
    }

    int j = s;
    for (; j + 8 <= e; j += 8) {
        int s0 = srow[j + q];
        int s1 = srow[j + 4 + q];
        uint4 v0 = y4[(size_t)s0 * 16 + l16];
        uint4 v1 = y4[(size_t)s1 * 16 + l16];
        unsigned int p0[4] = {v0.x, v0.y, v0.z, v0.w};
        unsigned int p1[4] = {v1.x, v1.y, v1.z, v1.w};
#pragma unroll
        for (int t = 0; t < 4; ++t) {
            acc[2 * t]     += __uint_as_float(p0[t] << 16);
            acc[2 * t + 1] += __uint_as_float(p0[t] & 0xffff0000u);
            acc[2 * t]     += __uint_as_float(p1[t] << 16);
            acc[2 * t + 1] += __uint_as_float(p1[t] & 0xffff0000u);
        }
    }
    for (; j + 4 <= e; j += 4) {
        int s0 = srow[j + q];
        uint4 v0 = y4[(size_t)s0 * 16 + l16];
        unsigned int p0[4] = {v0.x, v0.y, v0.z, v0.w};
#pragma unroll
        for (int t = 0; t < 4; ++t) {
            acc[2 * t]     += __uint_as_float(p0[t] << 16);
            acc[2 * t + 1] += __uint_as_float(p0[t] & 0xffff0000u);
        }
    }
    if (j + q < e) {
        int s0 = srow[j + q];
        uint4 v0 = y4[(size_t)s0 * 16 + l16];
        unsigned int p0[4] = {v0.x, v0.y, v0.z, v0.w};
#pragma unroll
        for (int t = 0; t < 4; ++t) {
            acc[2 * t]     += __uint_as_float(p0[t] << 16);
            acc[2 * t + 1] += __uint_as_float(p0[t] & 0xffff0000u);
        }
    }

    // fold quarters: lanes l, l+16, l+32, l+48 hold the same channel group
#pragma unroll
    for (int k = 0; k < 8; ++k) {
        acc[k] += __shfl_xor(acc[k], 16, 64);
        acc[k] += __shfl_xor(acc[k], 32, 64);
    }

    if (q == 0) {
        float sc = rsqrtf((float)(e - s + 1));
        int c0 = l16 * 8;
        float4 b0 = *(const float4*)&b[c0];
        float4 b1 = *(const float4*)&b[c0 + 4];
        float4 o0, o1;
        o0.x = fmaxf(fmaf(sc, acc[0], b0.x), 0.f);
        o0.y = fmaxf(fmaf(sc, acc[1], b0.y), 0.f);
        o0.z = fmaxf(fmaf(sc, acc[2], b0.z), 0.f);
        o0.w = fmaxf(fmaf(sc, acc[3], b0.w), 0.f);
        o1.x = fmaxf(fmaf(sc, acc[4], b1.x), 0.f);
        o1.y = fmaxf(fmaf(sc, acc[5], b1.y), 0.f);
        o1.z = fmaxf(fmaf(sc, acc[6], b1.z), 0.f);
        o1.w = fmaxf(fmaf(sc, acc[7], b1.w), 0.f);
        float4* orow = (float4*)&out[(size_t)i * DCH + c0];
        orow[0] = o0;
        orow[1] = o1;
    }
}

extern "C" void kernel_launch(void* const* d_in, const int* in_sizes, int n_in,
                              void* d_out, int out_size, void* d_ws, size_t ws_size,
                              hipStream_t stream) {
    const float* x = (const float*)d_in[0];
    const int* ei  = (const int*)d_in[1];
    const float* W = (const float*)d_in[2];
    const float* b = (const float*)d_in[3];
    float* out = (float*)d_out;

    int n = in_sizes[0] / DCH;     // 100000
    int E = in_sizes[1] / 2;       // 1600000
    const int* row = ei;           // sources
    const int* col = ei + E;       // destinations

    int B = (n + NODES_PER_BUCKET - 1) / NODES_PER_BUCKET;   // 391
    int CAP = 6144;

    char* ws = (char*)d_ws;
    size_t o = 0;
    auto alloc = [&](size_t bytes) -> void* {
        o = (o + 255) & ~(size_t)255;
        void* p = ws + o;
        o += bytes;
        return p;
    };
    int* cnt     = (int*)alloc((size_t)n * 4);
    int* off     = (int*)alloc((size_t)(n + 1) * 4);
    int* bs      = (int*)alloc(1024 * 4);
    int* gcount  = (int*)alloc((size_t)B * 4);
    int* srow    = (int*)alloc((size_t)E * 4);
    unsigned short* Wf = (unsigned short*)alloc((size_t)DCH * DCH * 2);
    unsigned short* y  = (unsigned short*)alloc((size_t)n * DCH * 2);
    // coarse buffer aliases y: dead before k_gemm_mfma writes y (9.6 MB <= 25.6 MB)
    unsigned int* coarse = (unsigned int*)y;

    hipMemsetAsync(cnt, 0, (size_t)n * 4, stream);
    hipMemsetAsync(gcount, 0, (size_t)B * 4, stream);
    k_wfrag<<<32, 64, 0, stream>>>(W, Wf);
    k_hist<<<(E + 255) / 256, 256, 0, stream>>>(col, cnt, E);
    int nb = (n + 1023) / 1024;    // 98
    k_scan1<<<nb, 1024, 0, stream>>>(cnt, off, bs, n);
    k_scan2<<<1, 1024, 0, stream>>>(bs, nb);
    k_scan3<<<nb, 1024, 0, stream>>>(off, bs, n);
    int nt = (E + T_PART - 1) / T_PART;  // 391
    k_part<<<nt, 512, 0, stream>>>(row, col, coarse, gcount, E, B, CAP);
    k_csr<<<B, 256, 0, stream>>>(coarse, gcount, off, srow, n, CAP);
    k_gemm_mfma<<<(n + 63) / 64, 256, 0, stream>>>(x, Wf, cnt, y, n);
    k_agg<<<(n + 3) / 4, 256, 0, stream>>>((const uint4*)y, srow, off, b, out, n, E);
}

// Round 5
// 288.382 us; speedup vs baseline: 1.5891x; 1.0023x over previous
//
#include <hip/hip_runtime.h>

#define DCH 128
#define T_PART 4096
#define B_MAX 512
#define CAPC 6144
#define CAP_Q 1536

typedef short bf16x8 __attribute__((ext_vector_type(8)));
typedef float f32x4 __attribute__((ext_vector_type(4)));

__device__ inline unsigned short f2bf(float f) {
    unsigned int u = __float_as_uint(f);
    unsigned int r = (u + 0x7fffu + ((u >> 16) & 1u)) >> 16;
    return (unsigned short)r;
}

// ---------------- init: zero cnt/gcount + pack W into MFMA B-frag order ----------
// Frag (nt,ks): lane holds B[k=ks*32+(lane>>4)*8+j][n=nt*16+(lane&15)], j=0..7.
__global__ __launch_bounds__(256) void k_init(const float* __restrict__ W,
                                              unsigned short* __restrict__ Wf,
                                              int* __restrict__ cnt,
                                              int* __restrict__ gcount,
                                              int n, int B) {
    int idx = blockIdx.x * 256 + threadIdx.x;
    for (int i = idx; i < n; i += gridDim.x * 256) cnt[i] = 0;
    if (idx < B) gcount[idx] = 0;
    if (blockIdx.x < 32 && threadIdx.x < 64) {
        int frag = blockIdx.x;     // 0..31 = nt*4+ks
        int lane = threadIdx.x;
        int nt = frag >> 2, ks = frag & 3;
        int nn = nt * 16 + (lane & 15);
        int k0 = ks * 32 + ((lane >> 4) * 8);
        unsigned short tmp[8];
#pragma unroll
        for (int j = 0; j < 8; ++j) tmp[j] = f2bf(W[(size_t)(k0 + j) * DCH + nn]);
        *(uint4*)&Wf[((size_t)frag * 64 + lane) * 8] = *(const uint4*)tmp;
    }
}

// ---------------- coarse partition + fused degree histogram ----------------
// Bins edges by dest>>8 into B buckets; one global atomic reservation per
// bucket per tile + contiguous burst writes (kills 16x write amplification).
// Also accumulates global in-degree cnt[] (was a separate k_hist dispatch).
__global__ __launch_bounds__(512) void k_part(const int* __restrict__ row,
                                              const int* __restrict__ col,
                                              unsigned int* __restrict__ coarse,
                                              int* __restrict__ gcount,
                                              int* __restrict__ cnt,
                                              int E, int B) {
    __shared__ int hist[B_MAX];
    __shared__ int basex[B_MAX];
    __shared__ int curx[B_MAX];
    __shared__ int gb[B_MAX];
    __shared__ unsigned int spack[T_PART];
    __shared__ unsigned short sbuck[T_PART];

    int tid = threadIdx.x;
    int base_e = blockIdx.x * T_PART;
    int tileCnt = min(T_PART, E - base_e);

    hist[tid] = 0;
    __syncthreads();

    int er[8], ec[8];
#pragma unroll
    for (int i = 0; i < 8; ++i) {
        int e = base_e + tid + i * 512;
        if (e < E) {
            er[i] = row[e];
            ec[i] = col[e];
            atomicAdd(&hist[ec[i] >> 8], 1);
            atomicAdd(&cnt[ec[i]], 1);       // fused k_hist
        } else {
            er[i] = -1;
            ec[i] = 0;
        }
    }
    __syncthreads();

    int v = hist[tid];
    basex[tid] = v;
    __syncthreads();
    for (int o = 1; o < 512; o <<= 1) {
        int t = (tid >= o) ? basex[tid - o] : 0;
        __syncthreads();
        basex[tid] += t;
        __syncthreads();
    }
    int excl = basex[tid] - v;
    __syncthreads();
    basex[tid] = excl;
    curx[tid] = excl;
    if (tid < B) gb[tid] = (v > 0) ? atomicAdd(&gcount[tid], v) : 0;
    else gb[tid] = 0;
    __syncthreads();

#pragma unroll
    for (int i = 0; i < 8; ++i) {
        if (er[i] >= 0) {
            int b = ec[i] >> 8;
            int slot = atomicAdd(&curx[b], 1);
            spack[slot] = ((unsigned int)er[i] << 8) | (unsigned int)(ec[i] & 255);
            sbuck[slot] = (unsigned short)b;
        }
    }
    __syncthreads();

    for (int s = tid; s < tileCnt; s += 512) {
        int b = sbuck[s];
        int dst = gb[b] + (s - basex[b]);
        if (dst < CAPC) coarse[(size_t)b * CAPC + dst] = spack[s];
    }
}

// ---------------- y = bf16((x @ W) * rsqrt(deg))  via MFMA ----------------
__global__ __launch_bounds__(256) void k_gemm_mfma(const float* __restrict__ x,
                                                   const unsigned short* __restrict__ Wf,
                                                   const int* __restrict__ cnt,
                                                   unsigned short* __restrict__ y,
                                                   int n) {
    int tid = threadIdx.x;
    int wv = tid >> 6;
    int lane = tid & 63;
    int rowBase = blockIdx.x * 64 + wv * 16;
    int m = rowBase + (lane & 15);
    int mc = (m < n) ? m : (n - 1);
    int kq = (lane >> 4) * 8;

    f32x4 acc[8];
    f32x4 zero = {0.f, 0.f, 0.f, 0.f};
#pragma unroll
    for (int t = 0; t < 8; ++t) acc[t] = zero;

    const bf16x8* wfv = (const bf16x8*)Wf;
#pragma unroll
    for (int ks = 0; ks < 4; ++ks) {
        int kbase = ks * 32 + kq;
        float4 lo = *(const float4*)&x[(size_t)mc * DCH + kbase];
        float4 hi = *(const float4*)&x[(size_t)mc * DCH + kbase + 4];
        bf16x8 a;
        a[0] = (short)f2bf(lo.x); a[1] = (short)f2bf(lo.y);
        a[2] = (short)f2bf(lo.z); a[3] = (short)f2bf(lo.w);
        a[4] = (short)f2bf(hi.x); a[5] = (short)f2bf(hi.y);
        a[6] = (short)f2bf(hi.z); a[7] = (short)f2bf(hi.w);
#pragma unroll
        for (int nt = 0; nt < 8; ++nt) {
            bf16x8 bfr = wfv[(nt * 4 + ks) * 64 + lane];
            acc[nt] = __builtin_amdgcn_mfma_f32_16x16x32_bf16(a, bfr, acc[nt], 0, 0, 0);
        }
    }

    int orow_base = rowBase + ((lane >> 4) * 4);
#pragma unroll
    for (int r = 0; r < 4; ++r) {
        int orow = orow_base + r;
        if (orow < n) {
            float s = rsqrtf((float)(cnt[orow] + 1));
#pragma unroll
            for (int nt = 0; nt < 8; ++nt) {
                y[(size_t)orow * DCH + nt * 16 + (lane & 15)] = f2bf(acc[nt][r] * s);
            }
        }
    }
}

// ---------------- fused CSR-in-LDS + gather-aggregate + bias + ReLU ----------
// Block = quarter of a coarse bucket (64 dests). Stages the bucket's packed
// entries in LDS, filters its 64 dests, builds the per-dest grouping with an
// LDS histogram + wave scan (replaces scan1/2/3 + k_csr dispatches + the srow
// global round-trip). Then per dest: quarter-wave uint4 gather (one wave-load
// = 4 source rows = 1 KB), shfl_xor fold, out = relu(dinv*acc + b).
__global__ __launch_bounds__(256) void k_agg(const uint4* __restrict__ y4,
                                             const unsigned int* __restrict__ coarse,
                                             const int* __restrict__ gcount,
                                             const float* __restrict__ b,
                                             float* __restrict__ out, int n) {
    __shared__ unsigned int ent[CAPC];
    __shared__ int hist_[64], base_[64], cur_[64];
    __shared__ int lsrc[CAP_Q];

    int bkt = blockIdx.x >> 2;
    int qd = blockIdx.x & 3;
    int tid = threadIdx.x;
    int cntb = min(gcount[bkt], CAPC);

    for (int s = tid; s < cntb; s += 256) ent[s] = coarse[(size_t)bkt * CAPC + s];
    if (tid < 64) hist_[tid] = 0;
    __syncthreads();

    for (int s = tid; s < cntb; s += 256) {
        int dlow = ent[s] & 255;
        if ((dlow >> 6) == qd) atomicAdd(&hist_[dlow & 63], 1);
    }
    __syncthreads();

    if (tid < 64) {               // wave 0: inclusive shfl scan over 64 counts
        int v = hist_[tid];
        int xv = v;
#pragma unroll
        for (int o = 1; o < 64; o <<= 1) {
            int t = __shfl_up(xv, o, 64);
            if (tid >= o) xv += t;
        }
        base_[tid] = xv - v;
        cur_[tid] = xv - v;
    }
    __syncthreads();

    for (int s = tid; s < cntb; s += 256) {
        unsigned int p = ent[s];
        int dlow = p & 255;
        if ((dlow >> 6) == qd) {
            int slot = atomicAdd(&cur_[dlow & 63], 1);
            if (slot < CAP_Q) lsrc[slot] = (int)(p >> 8);
        }
    }
    __syncthreads();

    int wv = tid >> 6;
    int lane = tid & 63;
    int q = lane >> 4;
    int l16 = lane & 15;

    for (int t = 0; t < 16; ++t) {
        int d6 = wv + 4 * t;
        int i = (bkt << 8) + (qd << 6) + d6;
        if (i >= n) continue;
        int s = base_[d6];
        int deg = hist_[d6];
        int e = s + deg;

        float acc[8];
#pragma unroll
        for (int k = 0; k < 8; ++k) acc[k] = 0.f;

        if (q == 0) {             // self-loop
            uint4 v = y4[(size_t)i * 16 + l16];
            unsigned int p[4] = {v.x, v.y, v.z, v.w};
#pragma unroll
            for (int c = 0; c < 4; ++c) {
                acc[2 * c]     += __uint_as_float(p[c] << 16);
                acc[2 * c + 1] += __uint_as_float(p[c] & 0xffff0000u);
            }
        }

        int j = s;
        for (; j + 8 <= e; j += 8) {
            int s0 = lsrc[j + q];
            int s1 = lsrc[j + 4 + q];
            uint4 v0 = y4[(size_t)s0 * 16 + l16];
            uint4 v1 = y4[(size_t)s1 * 16 + l16];
            unsigned int p0[4] = {v0.x, v0.y, v0.z, v0.w};
            unsigned int p1[4] = {v1.x, v1.y, v1.z, v1.w};
#pragma unroll
            for (int c = 0; c < 4; ++c) {
                acc[2 * c]     += __uint_as_float(p0[c] << 16);
                acc[2 * c + 1] += __uint_as_float(p0[c] & 0xffff0000u);
                acc[2 * c]     += __uint_as_float(p1[c] << 16);
                acc[2 * c + 1] += __uint_as_float(p1[c] & 0xffff0000u);
            }
        }
        for (; j + 4 <= e; j += 4) {
            int s0 = lsrc[j + q];
            uint4 v0 = y4[(size_t)s0 * 16 + l16];
            unsigned int p0[4] = {v0.x, v0.y, v0.z, v0.w};
#pragma unroll
            for (int c = 0; c < 4; ++c) {
                acc[2 * c]     += __uint_as_float(p0[c] << 16);
                acc[2 * c + 1] += __uint_as_float(p0[c] & 0xffff0000u);
            }
        }
        if (j + q < e) {
            int s0 = lsrc[j + q];
            uint4 v0 = y4[(size_t)s0 * 16 + l16];
            unsigned int p0[4] = {v0.x, v0.y, v0.z, v0.w};
#pragma unroll
            for (int c = 0; c < 4; ++c) {
                acc[2 * c]     += __uint_as_float(p0[c] << 16);
                acc[2 * c + 1] += __uint_as_float(p0[c] & 0xffff0000u);
            }
        }

#pragma unroll
        for (int k = 0; k < 8; ++k) {
            acc[k] += __shfl_xor(acc[k], 16, 64);
            acc[k] += __shfl_xor(acc[k], 32, 64);
        }

        if (q == 0) {
            float sc = rsqrtf((float)(deg + 1));
            int c0 = l16 * 8;
            float4 b0 = *(const float4*)&b[c0];
            float4 b1 = *(const float4*)&b[c0 + 4];
            float4 o0, o1;
            o0.x = fmaxf(fmaf(sc, acc[0], b0.x), 0.f);
            o0.y = fmaxf(fmaf(sc, acc[1], b0.y), 0.f);
            o0.z = fmaxf(fmaf(sc, acc[2], b0.z), 0.f);
            o0.w = fmaxf(fmaf(sc, acc[3], b0.w), 0.f);
            o1.x = fmaxf(fmaf(sc, acc[4], b1.x), 0.f);
            o1.y = fmaxf(fmaf(sc, acc[5], b1.y), 0.f);
            o1.z = fmaxf(fmaf(sc, acc[6], b1.z), 0.f);
            o1.w = fmaxf(fmaf(sc, acc[7], b1.w), 0.f);
            float4* orow = (float4*)&out[(size_t)i * DCH + c0];
            orow[0] = o0;
            orow[1] = o1;
        }
    }
}

extern "C" void kernel_launch(void* const* d_in, const int* in_sizes, int n_in,
                              void* d_out, int out_size, void* d_ws, size_t ws_size,
                              hipStream_t stream) {
    const float* x = (const float*)d_in[0];
    const int* ei  = (const int*)d_in[1];
    const float* W = (const float*)d_in[2];
    const float* b = (const float*)d_in[3];
    float* out = (float*)d_out;

    int n = in_sizes[0] / DCH;     // 100000
    int E = in_sizes[1] / 2;       // 1600000
    const int* row = ei;           // sources
    const int* col = ei + E;       // destinations

    int B = (n + 255) / 256;       // 391 coarse buckets

    char* ws = (char*)d_ws;
    size_t o = 0;
    auto alloc = [&](size_t bytes) -> void* {
        o = (o + 255) & ~(size_t)255;
        void* p = ws + o;
        o += bytes;
        return p;
    };
    int* cnt     = (int*)alloc((size_t)n * 4);
    int* gcount  = (int*)alloc((size_t)B * 4);
    unsigned int* coarse = (unsigned int*)alloc((size_t)B * CAPC * 4);  // 9.6 MB
    unsigned short* Wf = (unsigned short*)alloc((size_t)DCH * DCH * 2);
    unsigned short* y  = (unsigned short*)alloc((size_t)n * DCH * 2);   // 25.6 MB

    // 4 dispatches total (was 11): launch-gap overhead was ~40% of runtime.
    k_init<<<256, 256, 0, stream>>>(W, Wf, cnt, gcount, n, B);
    int nt = (E + T_PART - 1) / T_PART;  // 391
    k_part<<<nt, 512, 0, stream>>>(row, col, coarse, gcount, cnt, E, B);
    k_gemm_mfma<<<(n + 63) / 64, 256, 0, stream>>>(x, Wf, cnt, y, n);
    k_agg<<<B * 4, 256, 0, stream>>>((const uint4*)y, coarse, gcount, b, out, n);
}

// Round 6
// 213.711 us; speedup vs baseline: 2.1443x; 1.3494x over previous
//
#include <hip/hip_runtime.h>

#define DCH 128
#define T_PART 4096
#define B_MAX 512
#define CAPC 6144

typedef short bf16x8 __attribute__((ext_vector_type(8)));
typedef float f32x4 __attribute__((ext_vector_type(4)));

__device__ inline unsigned short f2bf(float f) {
    unsigned int u = __float_as_uint(f);
    unsigned int r = (u + 0x7fffu + ((u >> 16) & 1u)) >> 16;
    return (unsigned short)r;
}

// ---------------- init: zero gcount + pack W into MFMA B-frag order ----------
// Frag (nt,ks): lane holds B[k=ks*32+(lane>>4)*8+j][n=nt*16+(lane&15)], j=0..7.
__global__ __launch_bounds__(256) void k_init(const float* __restrict__ W,
                                              unsigned short* __restrict__ Wf,
                                              int* __restrict__ gcount, int B) {
    int idx = blockIdx.x * 256 + threadIdx.x;
    if (idx < B) gcount[idx] = 0;
    int frag = blockIdx.x * 4 + (threadIdx.x >> 6);   // 8 blocks x 4 frags
    if (frag < 32) {
        int lane = threadIdx.x & 63;
        int nt = frag >> 2, ks = frag & 3;
        int nn = nt * 16 + (lane & 15);
        int k0 = ks * 32 + ((lane >> 4) * 8);
        unsigned short tmp[8];
#pragma unroll
        for (int j = 0; j < 8; ++j) tmp[j] = f2bf(W[(size_t)(k0 + j) * DCH + nn]);
        *(uint4*)&Wf[((size_t)frag * 64 + lane) * 8] = *(const uint4*)tmp;
    }
}

// ---------------- coarse partition (wave-scan version, no global hist) --------
__global__ __launch_bounds__(512) void k_part(const int* __restrict__ row,
                                              const int* __restrict__ col,
                                              unsigned int* __restrict__ coarse,
                                              int* __restrict__ gcount,
                                              int E, int B) {
    __shared__ int hist[B_MAX];
    __shared__ int basex[B_MAX];
    __shared__ int curx[B_MAX];
    __shared__ int gb[B_MAX];
    __shared__ int wsum[8];
    __shared__ unsigned int spack[T_PART];
    __shared__ unsigned short sbuck[T_PART];

    int tid = threadIdx.x;
    int wv = tid >> 6, lane = tid & 63;
    int base_e = blockIdx.x * T_PART;
    int tileCnt = min(T_PART, E - base_e);

    hist[tid] = 0;
    __syncthreads();

    int er[8], ec[8];
#pragma unroll
    for (int i = 0; i < 8; ++i) {
        int e = base_e + tid + i * 512;
        if (e < E) {
            er[i] = row[e];
            ec[i] = col[e];
            atomicAdd(&hist[ec[i] >> 8], 1);
        } else {
            er[i] = -1;
            ec[i] = 0;
        }
    }
    __syncthreads();

    // exclusive scan over hist[512]: per-wave shfl scan + cross-wave offsets
    int v = hist[tid];
    int x = v;
#pragma unroll
    for (int o = 1; o < 64; o <<= 1) {
        int t = __shfl_up(x, o, 64);
        if (lane >= o) x += t;
    }
    if (lane == 63) wsum[wv] = x;
    __syncthreads();
    int add = 0;
    for (int w = 0; w < wv; ++w) add += wsum[w];
    int excl = x - v + add;
    basex[tid] = excl;
    curx[tid] = excl;
    if (tid < B) gb[tid] = (v > 0) ? atomicAdd(&gcount[tid], v) : 0;
    else gb[tid] = 0;
    __syncthreads();

#pragma unroll
    for (int i = 0; i < 8; ++i) {
        if (er[i] >= 0) {
            int b = ec[i] >> 8;
            int slot = atomicAdd(&curx[b], 1);
            spack[slot] = ((unsigned int)er[i] << 8) | (unsigned int)(ec[i] & 255);
            sbuck[slot] = (unsigned short)b;
        }
    }
    __syncthreads();

    for (int s = tid; s < tileCnt; s += 512) {
        int b = sbuck[s];
        int dst = gb[b] + (s - basex[b]);
        if (dst < CAPC) coarse[(size_t)b * CAPC + dst] = spack[s];
    }
}

// ---------------- bucket -> exact CSR + degree + row offsets ----------------
// One block per bucket. Derives: cnt[node]=in-degree, off[node]=global CSR
// start, srow[]=sources grouped by dest. Replaces scan1/2/3 + k_hist chain.
__global__ __launch_bounds__(512) void k_csr(const unsigned int* __restrict__ coarse,
                                             const int* __restrict__ gcount,
                                             int* __restrict__ srow,
                                             int* __restrict__ off,
                                             int* __restrict__ cnt,
                                             int n, int B) {
    __shared__ unsigned int ent[CAPC];
    __shared__ int h[256], cur[256];
    __shared__ int red1[8], red2[4];
    __shared__ int bbase_s;

    int b = blockIdx.x;
    int tid = threadIdx.x;
    int wv = tid >> 6, lane = tid & 63;

    // bucket base = sum of gcount[0..b)
    int part = 0;
    for (int i = tid; i < b; i += 512) part += gcount[i];
#pragma unroll
    for (int o = 1; o < 64; o <<= 1) part += __shfl_xor(part, o, 64);
    if (lane == 0) red1[wv] = part;
    if (tid < 256) h[tid] = 0;
    __syncthreads();
    if (tid == 0) {
        int s = 0;
        for (int w = 0; w < 8; ++w) s += red1[w];
        bbase_s = s;
    }
    int cntb = min(gcount[b], CAPC);
    for (int s = tid; s < cntb; s += 512) ent[s] = coarse[(size_t)b * CAPC + s];
    __syncthreads();

    for (int s = tid; s < cntb; s += 512) atomicAdd(&h[ent[s] & 255], 1);
    __syncthreads();

    int x = 0, v = 0;
    if (tid < 256) {
        v = h[tid];
        x = v;
#pragma unroll
        for (int o = 1; o < 64; o <<= 1) {
            int t = __shfl_up(x, o, 64);
            if (lane >= o) x += t;
        }
        if (lane == 63) red2[wv] = x;
    }
    __syncthreads();
    if (tid < 256) {
        int add = 0;
        for (int w = 0; w < wv; ++w) add += red2[w];
        int excl = x - v + add;
        cur[tid] = excl;
        int node = (b << 8) + tid;
        if (node < n) {
            cnt[node] = v;
            off[node] = bbase_s + excl;
        }
    }
    __syncthreads();

    int bbase = bbase_s;
    for (int s = tid; s < cntb; s += 512) {
        unsigned int p = ent[s];
        int d = p & 255;
        int slot = atomicAdd(&cur[d], 1);
        srow[bbase + slot] = (int)(p >> 8);
    }
}

// ---------------- y = bf16((x @ W) * rsqrt(deg))  via MFMA ----------------
__global__ __launch_bounds__(256) void k_gemm_mfma(const float* __restrict__ x,
                                                   const unsigned short* __restrict__ Wf,
                                                   const int* __restrict__ cnt,
                                                   unsigned short* __restrict__ y,
                                                   int n) {
    int tid = threadIdx.x;
    int wv = tid >> 6;
    int lane = tid & 63;
    int rowBase = blockIdx.x * 64 + wv * 16;
    int m = rowBase + (lane & 15);
    int mc = (m < n) ? m : (n - 1);
    int kq = (lane >> 4) * 8;

    f32x4 acc[8];
    f32x4 zero = {0.f, 0.f, 0.f, 0.f};
#pragma unroll
    for (int t = 0; t < 8; ++t) acc[t] = zero;

    const bf16x8* wfv = (const bf16x8*)Wf;
#pragma unroll
    for (int ks = 0; ks < 4; ++ks) {
        int kbase = ks * 32 + kq;
        float4 lo = *(const float4*)&x[(size_t)mc * DCH + kbase];
        float4 hi = *(const float4*)&x[(size_t)mc * DCH + kbase + 4];
        bf16x8 a;
        a[0] = (short)f2bf(lo.x); a[1] = (short)f2bf(lo.y);
        a[2] = (short)f2bf(lo.z); a[3] = (short)f2bf(lo.w);
        a[4] = (short)f2bf(hi.x); a[5] = (short)f2bf(hi.y);
        a[6] = (short)f2bf(hi.z); a[7] = (short)f2bf(hi.w);
#pragma unroll
        for (int nt = 0; nt < 8; ++nt) {
            bf16x8 bfr = wfv[(nt * 4 + ks) * 64 + lane];
            acc[nt] = __builtin_amdgcn_mfma_f32_16x16x32_bf16(a, bfr, acc[nt], 0, 0, 0);
        }
    }

    int orow_base = rowBase + ((lane >> 4) * 4);
#pragma unroll
    for (int r = 0; r < 4; ++r) {
        int orow = orow_base + r;
        if (orow < n) {
            float s = rsqrtf((float)(cnt[orow] + 1));
#pragma unroll
            for (int nt = 0; nt < 8; ++nt) {
                y[(size_t)orow * DCH + nt * 16 + (lane & 15)] = f2bf(acc[nt][r] * s);
            }
        }
    }
}

// ---------------- per-node gather-aggregate + bias + ReLU (R4 winner) --------
// One wave per node; quarter-wave q handles edge j+q via uint4 loads (one
// wave-load = 4 source rows = 1 KB); shfl_xor(16/32) folds quarters.
__global__ __launch_bounds__(256) void k_agg(const uint4* __restrict__ y4,
                                             const int* __restrict__ srow,
                                             const int* __restrict__ off,
                                             const float* __restrict__ b,
                                             float* __restrict__ out, int n, int E) {
    int i = blockIdx.x * 4 + (threadIdx.x >> 6);
    if (i >= n) return;
    int lane = threadIdx.x & 63;
    int q = lane >> 4;
    int l16 = lane & 15;
    int s = off[i];
    int e = (i + 1 < n) ? off[i + 1] : E;

    float acc[8];
#pragma unroll
    for (int k = 0; k < 8; ++k) acc[k] = 0.f;

    if (q == 0) {   // self-loop
        uint4 v = y4[(size_t)i * 16 + l16];
        unsigned int p[4] = {v.x, v.y, v.z, v.w};
#pragma unroll
        for (int t = 0; t < 4; ++t) {
            acc[2 * t]     += __uint_as_float(p[t] << 16);
            acc[2 * t + 1] += __uint_as_float(p[t] & 0xffff0000u);
        }
    }

    int j = s;
    for (; j + 8 <= e; j += 8) {
        int s0 = srow[j + q];
        int s1 = srow[j + 4 + q];
        uint4 v0 = y4[(size_t)s0 * 16 + l16];
        uint4 v1 = y4[(size_t)s1 * 16 + l16];
        unsigned int p0[4] = {v0.x, v0.y, v0.z, v0.w};
        unsigned int p1[4] = {v1.x, v1.y, v1.z, v1.w};
#pragma unroll
        for (int t = 0; t < 4; ++t) {
            acc[2 * t]     += __uint_as_float(p0[t] << 16);
            acc[2 * t + 1] += __uint_as_float(p0[t] & 0xffff0000u);
            acc[2 * t]     += __uint_as_float(p1[t] << 16);
            acc[2 * t + 1] += __uint_as_float(p1[t] & 0xffff0000u);
        }
    }
    for (; j + 4 <= e; j += 4) {
        int s0 = srow[j + q];
        uint4 v0 = y4[(size_t)s0 * 16 + l16];
        unsigned int p0[4] = {v0.x, v0.y, v0.z, v0.w};
#pragma unroll
        for (int t = 0; t < 4; ++t) {
            acc[2 * t]     += __uint_as_float(p0[t] << 16);
            acc[2 * t + 1] += __uint_as_float(p0[t] & 0xffff0000u);
        }
    }
    if (j + q < e) {
        int s0 = srow[j + q];
        uint4 v0 = y4[(size_t)s0 * 16 + l16];
        unsigned int p0[4] = {v0.x, v0.y, v0.z, v0.w};
#pragma unroll
        for (int t = 0; t < 4; ++t) {
            acc[2 * t]     += __uint_as_float(p0[t] << 16);
            acc[2 * t + 1] += __uint_as_float(p0[t] & 0xffff0000u);
        }
    }

#pragma unroll
    for (int k = 0; k < 8; ++k) {
        acc[k] += __shfl_xor(acc[k], 16, 64);
        acc[k] += __shfl_xor(acc[k], 32, 64);
    }

    if (q == 0) {
        float sc = rsqrtf((float)(e - s + 1));
        int c0 = l16 * 8;
        float4 b0 = *(const float4*)&b[c0];
        float4 b1 = *(const float4*)&b[c0 + 4];
        float4 o0, o1;
        o0.x = fmaxf(fmaf(sc, acc[0], b0.x), 0.f);
        o0.y = fmaxf(fmaf(sc, acc[1], b0.y), 0.f);
        o0.z = fmaxf(fmaf(sc, acc[2], b0.z), 0.f);
        o0.w = fmaxf(fmaf(sc, acc[3], b0.w), 0.f);
        o1.x = fmaxf(fmaf(sc, acc[4], b1.x), 0.f);
        o1.y = fmaxf(fmaf(sc, acc[5], b1.y), 0.f);
        o1.z = fmaxf(fmaf(sc, acc[6], b1.z), 0.f);
        o1.w = fmaxf(fmaf(sc, acc[7], b1.w), 0.f);
        float4* orow = (float4*)&out[(size_t)i * DCH + c0];
        orow[0] = o0;
        orow[1] = o1;
    }
}

extern "C" void kernel_launch(void* const* d_in, const int* in_sizes, int n_in,
                              void* d_out, int out_size, void* d_ws, size_t ws_size,
                              hipStream_t stream) {
    const float* x = (const float*)d_in[0];
    const int* ei  = (const int*)d_in[1];
    const float* W = (const float*)d_in[2];
    const float* b = (const float*)d_in[3];
    float* out = (float*)d_out;

    int n = in_sizes[0] / DCH;     // 100000
    int E = in_sizes[1] / 2;       // 1600000
    const int* row = ei;           // sources
    const int* col = ei + E;       // destinations

    int B = (n + 255) / 256;       // 391 coarse buckets

    char* ws = (char*)d_ws;
    size_t o = 0;
    auto alloc = [&](size_t bytes) -> void* {
        o = (o + 255) & ~(size_t)255;
        void* p = ws + o;
        o += bytes;
        return p;
    };
    int* cnt     = (int*)alloc((size_t)n * 4);
    int* off     = (int*)alloc((size_t)(n + 1) * 4);
    int* gcount  = (int*)alloc((size_t)B * 4);
    int* srow    = (int*)alloc((size_t)E * 4);
    unsigned int* coarse = (unsigned int*)alloc((size_t)B * CAPC * 4);  // 9.6 MB
    unsigned short* Wf = (unsigned short*)alloc((size_t)DCH * DCH * 2);
    unsigned short* y  = (unsigned short*)alloc((size_t)n * DCH * 2);   // 25.6 MB

    int nt = (E + T_PART - 1) / T_PART;  // 391
    k_init<<<8, 256, 0, stream>>>(W, Wf, gcount, B);
    k_part<<<nt, 512, 0, stream>>>(row, col, coarse, gcount, E, B);
    k_csr<<<B, 512, 0, stream>>>(coarse, gcount, srow, off, cnt, n, B);
    k_gemm_mfma<<<(n + 63) / 64, 256, 0, stream>>>(x, Wf, cnt, y, n);
    k_agg<<<(n + 3) / 4, 256, 0, stream>>>((const uint4*)y, srow, off, b, out, n, E);
}